// Round 2
// baseline (746.257 us; speedup 1.0000x reference)
//
#include <hip/hip_runtime.h>

#define NCH 32
#define GT 128
#define NCELL (GT * GT * GT)  // 2,097,152 cells

// ticks[i] = -1 + i*0.015625 = (i-64)/64, exactly representable in f32.
__device__ __forceinline__ float tickf(int i) {
    return (float)(i - 64) * 0.015625f;
}

struct Dim {
    int il, ir;
    float dl, dr;
};

// Exact replica of the reference's searchsorted(side='left') + clip + dist logic.
// idx_right = smallest i with ticks[i] >= x  <=>  i >= 64x + 64  <=>  ceil(64x) + 64
// (64x is exact in f32: multiply by power of two).
__device__ __forceinline__ Dim dimcalc(float x) {
    Dim d;
    float t = ceilf(x * 64.0f);
    t = fminf(fmaxf(t, -1024.0f), 1024.0f);  // safety clamp before int convert
    int ir = (int)t + 64;
    ir = min(max(ir, 0), GT - 1);
    int il = max(ir - 1, 0);
    float dl = fmaxf(x - tickf(il), 0.0f);
    float dr = fmaxf(tickf(ir) - x, 0.0f);
    if (dl == 0.0f && dr == 0.0f) { dl = 1.0f; dr = 1.0f; }
    d.il = il; d.ir = ir; d.dl = dl; d.dr = dr;
    return d;
}

// ---------------------------------------------------------------------------
// Kernel 1: transpose grid [32][NCELL] -> gT [NCELL][32] (channel-innermost).
// Grid-stride over 64-cell tiles; block = 256 threads; LDS staging.
// ---------------------------------------------------------------------------
__global__ __launch_bounds__(256) void transpose_grid(const float* __restrict__ g,
                                                      float* __restrict__ gT,
                                                      int nTiles) {
    __shared__ float tile[64][33];  // +1 pad: conflict-free both phases
    const int tx = threadIdx.x & 63;   // cell within tile
    const int ty = threadIdx.x >> 6;   // 0..3
    const int c = threadIdx.x & 31;
    const int cellSub = threadIdx.x >> 5;  // 0..7

    for (int t = blockIdx.x; t < nTiles; t += gridDim.x) {
        const int tileBase = t * 64;
        // Load: coalesced 256B rows per channel (64 cells contiguous).
#pragma unroll
        for (int k = 0; k < 8; ++k) {
            int ch = k * 4 + ty;
            tile[tx][ch] = g[(size_t)ch * NCELL + tileBase + tx];
        }
        __syncthreads();
        // Store: each half-wave writes one cell's 32 channels = 128B contiguous.
#pragma unroll
        for (int k = 0; k < 8; ++k) {
            int cellLocal = k * 8 + cellSub;
            gT[(size_t)(tileBase + cellLocal) * 32 + c] = tile[cellLocal][c];
        }
        __syncthreads();
    }
}

// ---------------------------------------------------------------------------
// Kernel 2: interpolation from the transposed grid.
// 8 lanes per point; each lane owns 4 channels (one float4 per corner).
// Per corner: 8 lanes x 16B = 128B fully-coalesced chunk.
// ---------------------------------------------------------------------------
__global__ __launch_bounds__(256) void interp_kernel_t(const float* __restrict__ pts,
                                                       const float4* __restrict__ gT4,
                                                       float4* __restrict__ out4,
                                                       int N) {
    const int nWork = N * 8;
    for (int gid = blockIdx.x * 256 + threadIdx.x; gid < nWork; gid += gridDim.x * 256) {
        const int p = gid >> 3;
        const int sub = gid & 7;  // which float4 of the 32 channels

        const float x0 = pts[3 * (size_t)p + 0];
        const float x1 = pts[3 * (size_t)p + 1];
        const float x2 = pts[3 * (size_t)p + 2];
        const Dim d0 = dimcalc(x0);
        const Dim d1 = dimcalc(x1);
        const Dim d2 = dimcalc(x2);

        const int r0l = d0.il * (GT * GT), r0r = d0.ir * (GT * GT);
        const int r1l = d1.il * GT,        r1r = d1.ir * GT;

        float4 acc = make_float4(0.f, 0.f, 0.f, 0.f);
        // Corner order matches reference product([0,1],repeat=3): bit2=dim0 ... bit0=dim2.
#pragma unroll
        for (int corner = 0; corner < 8; ++corner) {
            const int b0 = (corner >> 2) & 1;
            const int b1 = (corner >> 1) & 1;
            const int b2 = corner & 1;
            const int cell = (b0 ? r0r : r0l) + (b1 ? r1r : r1l) + (b2 ? d2.ir : d2.il);
            // weight uses OPPOSITE-side distance (reference semantics)
            const float w = (b0 ? d0.dl : d0.dr) * (b1 ? d1.dl : d1.dr) * (b2 ? d2.dl : d2.dr);
            const float4 gv = gT4[(size_t)cell * 8 + sub];
            acc.x += gv.x * w;
            acc.y += gv.y * w;
            acc.z += gv.z * w;
            acc.w += gv.w * w;
        }
        const float denom = (d0.dl + d0.dr) * (d1.dl + d1.dr) * (d2.dl + d2.dr);
        const float inv = 1.0f / denom;  // exact IEEE divide, one per lane
        float4 r;
        r.x = acc.x * inv;
        r.y = acc.y * inv;
        r.z = acc.z * inv;
        r.w = acc.w * inv;
        out4[(size_t)p * 8 + sub] = r;
    }
}

// ---------------------------------------------------------------------------
// Fallback: gather directly from native [32][NCELL] layout (no workspace).
// ---------------------------------------------------------------------------
__global__ __launch_bounds__(256) void interp_kernel_direct(const float* __restrict__ pts,
                                                            const float* __restrict__ g,
                                                            float4* __restrict__ out4,
                                                            int N) {
    const int nWork = N * 8;
    for (int gid = blockIdx.x * 256 + threadIdx.x; gid < nWork; gid += gridDim.x * 256) {
        const int p = gid >> 3;
        const int sub = gid & 7;

        const float x0 = pts[3 * (size_t)p + 0];
        const float x1 = pts[3 * (size_t)p + 1];
        const float x2 = pts[3 * (size_t)p + 2];
        const Dim d0 = dimcalc(x0);
        const Dim d1 = dimcalc(x1);
        const Dim d2 = dimcalc(x2);

        const int r0l = d0.il * (GT * GT), r0r = d0.ir * (GT * GT);
        const int r1l = d1.il * GT,        r1r = d1.ir * GT;
        const int c0 = sub * 4;

        float4 acc = make_float4(0.f, 0.f, 0.f, 0.f);
#pragma unroll
        for (int corner = 0; corner < 8; ++corner) {
            const int b0 = (corner >> 2) & 1;
            const int b1 = (corner >> 1) & 1;
            const int b2 = corner & 1;
            const int cell = (b0 ? r0r : r0l) + (b1 ? r1r : r1l) + (b2 ? d2.ir : d2.il);
            const float w = (b0 ? d0.dl : d0.dr) * (b1 ? d1.dl : d1.dr) * (b2 ? d2.dl : d2.dr);
            acc.x += g[(size_t)(c0 + 0) * NCELL + cell] * w;
            acc.y += g[(size_t)(c0 + 1) * NCELL + cell] * w;
            acc.z += g[(size_t)(c0 + 2) * NCELL + cell] * w;
            acc.w += g[(size_t)(c0 + 3) * NCELL + cell] * w;
        }
        const float denom = (d0.dl + d0.dr) * (d1.dl + d1.dr) * (d2.dl + d2.dr);
        const float inv = 1.0f / denom;
        float4 r;
        r.x = acc.x * inv;
        r.y = acc.y * inv;
        r.z = acc.z * inv;
        r.w = acc.w * inv;
        out4[(size_t)p * 8 + sub] = r;
    }
}

extern "C" void kernel_launch(void* const* d_in, const int* in_sizes, int n_in,
                              void* d_out, int out_size, void* d_ws, size_t ws_size,
                              hipStream_t stream) {
    const float* pts = (const float*)d_in[0];   // [N][3] f32
    const float* grid = (const float*)d_in[1];  // [32][128][128][128] f32
    float4* out4 = (float4*)d_out;              // [N][32] f32
    const int N = in_sizes[0] / 3;

    const size_t needed = (size_t)NCELL * NCH * sizeof(float);  // 256 MiB
    const int nTiles = NCELL / 64;  // 32768
    const int interpWork = N * 8;
    const int interpBlocksFull = (interpWork + 255) / 256;
    const int interpBlocks = interpBlocksFull < 2048 ? interpBlocksFull : 2048;

    if (ws_size >= needed) {
        float* gT = (float*)d_ws;
        transpose_grid<<<1024, 256, 0, stream>>>(grid, gT, nTiles);
        interp_kernel_t<<<interpBlocks, 256, 0, stream>>>(pts, (const float4*)gT, out4, N);
    } else {
        interp_kernel_direct<<<interpBlocks, 256, 0, stream>>>(pts, grid, out4, N);
    }
}

// Round 4
// 671.480 us; speedup vs baseline: 1.1114x; 1.1114x over previous
//
#include <hip/hip_runtime.h>

#define NCH 32
#define GT 128
#define NCELL (GT * GT * GT)  // 2,097,152 cells
#define SLO 63                // lowest grid coord covered by the subgrid
#define SUB 65                // subgrid covers coords 63..127 inclusive
#define SUBROWS (SUB * SUB)   // 4225 (a,b) rows

// ticks[i] = -1 + i*0.015625 = (i-64)/64, exactly representable in f32.
__device__ __forceinline__ float tickf(int i) {
    return (float)(i - 64) * 0.015625f;
}

struct Dim {
    int il, ir;
    float dl, dr;
};

// Exact replica of the reference's searchsorted(side='left') + clip + dist logic.
// idx_right = smallest i with ticks[i] >= x  <=>  ceil(64x) + 64  (64x exact in f32).
__device__ __forceinline__ Dim dimcalc(float x) {
    Dim d;
    float t = ceilf(x * 64.0f);
    t = fminf(fmaxf(t, -1024.0f), 1024.0f);  // safety clamp before int convert
    int ir = (int)t + 64;
    ir = min(max(ir, 0), GT - 1);
    int il = max(ir - 1, 0);
    float dl = fmaxf(x - tickf(il), 0.0f);
    float dr = fmaxf(tickf(ir) - x, 0.0f);
    if (dl == 0.0f && dr == 0.0f) { dl = 1.0f; dr = 1.0f; }
    d.il = il; d.ir = ir; d.dl = dl; d.dr = dr;
    return d;
}

// ---------------------------------------------------------------------------
// Kernel 1: transpose ONLY the [63..127]^3 subgrid into channel-innermost
// layout: sub[((a*65+b)*65+c)*32 + ch], a/b/c = grid coord - 63.
// One block per (a,b) row. ~70 MB total traffic (vs 512 MB full transpose).
// ---------------------------------------------------------------------------
__global__ __launch_bounds__(256) void transpose_sub(const float* __restrict__ g,
                                                     float* __restrict__ sub) {
    const int ab = blockIdx.x;          // 0..4224
    const int a = ab / SUB, b = ab % SUB;
    __shared__ float tile[SUB][NCH + 1];  // +1 pad: conflict-free both phases
    const size_t srcRow = ((size_t)(SLO + a) * GT + (SLO + b)) * GT + SLO;

    // Load: per channel a contiguous 260B row of 65 floats.
    for (int idx = threadIdx.x; idx < NCH * SUB; idx += 256) {
        const int ch = idx / SUB, c = idx - ch * SUB;
        tile[c][ch] = g[(size_t)ch * NCELL + srcRow + c];
    }
    __syncthreads();

    // Store: fully contiguous 8320B per row (dst linear in idx).
    const size_t dstBase = (size_t)ab * SUB * NCH;
    for (int idx = threadIdx.x; idx < SUB * NCH; idx += 256) {
        const int c = idx >> 5, ch = idx & 31;
        sub[dstBase + idx] = tile[c][ch];
    }
}

// ---------------------------------------------------------------------------
// Kernel 2: interpolation. 4 lanes per point, each lane owns 8 channels as
// two float4s per corner (16 outstanding loads/lane for latency hiding).
// Per corner: 4 lanes x 2 x 16B = 128B, one cache line.
// Points outside the subgrid range (never for this data) take a native-layout
// fallback gather for full generality.
// ---------------------------------------------------------------------------
__global__ __launch_bounds__(256) void interp4(const float* __restrict__ pts,
                                               const float4* __restrict__ sub4,
                                               const float* __restrict__ g,
                                               float4* __restrict__ out4,
                                               int N) {
    const int nWork = N * 4;
    for (int gid = blockIdx.x * 256 + threadIdx.x; gid < nWork; gid += gridDim.x * 256) {
        const int p = gid >> 2;
        const int sq = gid & 3;  // lane's quarter: float4s sq and sq+4

        const float x0 = pts[3 * (size_t)p + 0];
        const float x1 = pts[3 * (size_t)p + 1];
        const float x2 = pts[3 * (size_t)p + 2];
        const Dim d0 = dimcalc(x0);
        const Dim d1 = dimcalc(x1);
        const Dim d2 = dimcalc(x2);

        float4 acc0 = make_float4(0.f, 0.f, 0.f, 0.f);
        float4 acc1 = make_float4(0.f, 0.f, 0.f, 0.f);

        const bool fast = (d0.il >= SLO) & (d1.il >= SLO) & (d2.il >= SLO);
        if (fast) {
            const int r0l = (d0.il - SLO) * (SUB * SUB), r0r = (d0.ir - SLO) * (SUB * SUB);
            const int r1l = (d1.il - SLO) * SUB,         r1r = (d1.ir - SLO) * SUB;
            const int c2l = d2.il - SLO,                 c2r = d2.ir - SLO;
#pragma unroll
            for (int corner = 0; corner < 8; ++corner) {
                const int b0 = (corner >> 2) & 1;
                const int b1 = (corner >> 1) & 1;
                const int b2 = corner & 1;
                const int cell = (b0 ? r0r : r0l) + (b1 ? r1r : r1l) + (b2 ? c2r : c2l);
                const float w = (b0 ? d0.dl : d0.dr) * (b1 ? d1.dl : d1.dr) * (b2 ? d2.dl : d2.dr);
                const float4 ga = sub4[(size_t)cell * 8 + sq];
                const float4 gb = sub4[(size_t)cell * 8 + sq + 4];
                acc0.x += ga.x * w; acc0.y += ga.y * w; acc0.z += ga.z * w; acc0.w += ga.w * w;
                acc1.x += gb.x * w; acc1.y += gb.y * w; acc1.z += gb.z * w; acc1.w += gb.w * w;
            }
        } else {
            const int r0l = d0.il * (GT * GT), r0r = d0.ir * (GT * GT);
            const int r1l = d1.il * GT,        r1r = d1.ir * GT;
            const int ca = sq * 4;        // channels for acc0
            const int cb = sq * 4 + 16;   // channels for acc1
#pragma unroll
            for (int corner = 0; corner < 8; ++corner) {
                const int b0 = (corner >> 2) & 1;
                const int b1 = (corner >> 1) & 1;
                const int b2 = corner & 1;
                const int cell = (b0 ? r0r : r0l) + (b1 ? r1r : r1l) + (b2 ? d2.ir : d2.il);
                const float w = (b0 ? d0.dl : d0.dr) * (b1 ? d1.dl : d1.dr) * (b2 ? d2.dl : d2.dr);
                acc0.x += g[(size_t)(ca + 0) * NCELL + cell] * w;
                acc0.y += g[(size_t)(ca + 1) * NCELL + cell] * w;
                acc0.z += g[(size_t)(ca + 2) * NCELL + cell] * w;
                acc0.w += g[(size_t)(ca + 3) * NCELL + cell] * w;
                acc1.x += g[(size_t)(cb + 0) * NCELL + cell] * w;
                acc1.y += g[(size_t)(cb + 1) * NCELL + cell] * w;
                acc1.z += g[(size_t)(cb + 2) * NCELL + cell] * w;
                acc1.w += g[(size_t)(cb + 3) * NCELL + cell] * w;
            }
        }

        const float denom = (d0.dl + d0.dr) * (d1.dl + d1.dr) * (d2.dl + d2.dr);
        const float inv = 1.0f / denom;
        float4 r0, r1;
        r0.x = acc0.x * inv; r0.y = acc0.y * inv; r0.z = acc0.z * inv; r0.w = acc0.w * inv;
        r1.x = acc1.x * inv; r1.y = acc1.y * inv; r1.z = acc1.z * inv; r1.w = acc1.w * inv;
        out4[(size_t)p * 8 + sq] = r0;
        out4[(size_t)p * 8 + sq + 4] = r1;
    }
}

// ---------------------------------------------------------------------------
// Fallback when workspace is too small: gather directly from native layout.
// ---------------------------------------------------------------------------
__global__ __launch_bounds__(256) void interp_kernel_direct(const float* __restrict__ pts,
                                                            const float* __restrict__ g,
                                                            float4* __restrict__ out4,
                                                            int N) {
    const int nWork = N * 8;
    for (int gid = blockIdx.x * 256 + threadIdx.x; gid < nWork; gid += gridDim.x * 256) {
        const int p = gid >> 3;
        const int sub = gid & 7;

        const float x0 = pts[3 * (size_t)p + 0];
        const float x1 = pts[3 * (size_t)p + 1];
        const float x2 = pts[3 * (size_t)p + 2];
        const Dim d0 = dimcalc(x0);
        const Dim d1 = dimcalc(x1);
        const Dim d2 = dimcalc(x2);

        const int r0l = d0.il * (GT * GT), r0r = d0.ir * (GT * GT);
        const int r1l = d1.il * GT,        r1r = d1.ir * GT;
        const int c0 = sub * 4;

        float4 acc = make_float4(0.f, 0.f, 0.f, 0.f);
#pragma unroll
        for (int corner = 0; corner < 8; ++corner) {
            const int b0 = (corner >> 2) & 1;
            const int b1 = (corner >> 1) & 1;
            const int b2 = corner & 1;
            const int cell = (b0 ? r0r : r0l) + (b1 ? r1r : r1l) + (b2 ? d2.ir : d2.il);
            const float w = (b0 ? d0.dl : d0.dr) * (b1 ? d1.dl : d1.dr) * (b2 ? d2.dl : d2.dr);
            acc.x += g[(size_t)(c0 + 0) * NCELL + cell] * w;
            acc.y += g[(size_t)(c0 + 1) * NCELL + cell] * w;
            acc.z += g[(size_t)(c0 + 2) * NCELL + cell] * w;
            acc.w += g[(size_t)(c0 + 3) * NCELL + cell] * w;
        }
        const float denom = (d0.dl + d0.dr) * (d1.dl + d1.dr) * (d2.dl + d2.dr);
        const float inv = 1.0f / denom;
        float4 r;
        r.x = acc.x * inv; r.y = acc.y * inv; r.z = acc.z * inv; r.w = acc.w * inv;
        out4[(size_t)p * 8 + sub] = r;
    }
}

extern "C" void kernel_launch(void* const* d_in, const int* in_sizes, int n_in,
                              void* d_out, int out_size, void* d_ws, size_t ws_size,
                              hipStream_t stream) {
    const float* pts = (const float*)d_in[0];   // [N][3] f32
    const float* grid = (const float*)d_in[1];  // [32][128][128][128] f32
    float4* out4 = (float4*)d_out;              // [N][32] f32
    const int N = in_sizes[0] / 3;

    const size_t needed = (size_t)SUB * SUB * SUB * NCH * sizeof(float);  // ~35.2 MiB

    if (ws_size >= needed) {
        float* sub = (float*)d_ws;
        transpose_sub<<<SUBROWS, 256, 0, stream>>>(grid, sub);
        const int nWork = N * 4;
        const int blocksFull = (nWork + 255) / 256;
        const int blocks = blocksFull < 2048 ? blocksFull : 2048;
        interp4<<<blocks, 256, 0, stream>>>(pts, (const float4*)sub, grid, out4, N);
    } else {
        const int nWork = N * 8;
        const int blocksFull = (nWork + 255) / 256;
        const int blocks = blocksFull < 2048 ? blocksFull : 2048;
        interp_kernel_direct<<<blocks, 256, 0, stream>>>(pts, grid, out4, N);
    }
}